// Round 6
// baseline (533.984 us; speedup 1.0000x reference)
//
#include <hip/hip_runtime.h>
#include <hip/hip_bf16.h>
#include <math.h>

// ---------------------------------------------------------------------------
// Transformer block fwd: B=4,T=2048,D=1024,H=16,HS=64,FF=4096, fp32 in/out,
// bf16 MFMA internally. Residual path (x, h, out) kept fp32.
// R5: GEMM 256x256 / BK=64 / 8-wave / dbuf LDS.  R6: XCD-chunked swizzle.
// R7: gemm_n128 (full-chip) for N=1024 GEMMs, tri-buffer 2-ahead vmcnt(6).
// R8: attn glds16 dbuf staging + XOR LDS.  R9: P lane-local via vtg token
//     permutation (attn bank conflicts = 0 measured).
// R10: GEMM K-loops de-barriered. Ledger: within tile t all ds_reads hit
//     buf[cur], all staging hits buf[nxt] -> NO mid-tile cross-wave hazard;
//     ONE vmcnt + ONE barrier per K-tile suffices. All tile reads issued
//     up-front (both A-halves / both B col-sets in regs), stages issued,
//     then the full MFMA cluster under setprio; compiler emits fine-grained
//     lgkmcnt (m97 evidence) - no manual lgkm (rule-18 safe).
// ---------------------------------------------------------------------------

typedef unsigned short u16;
typedef __attribute__((ext_vector_type(8))) short s16x8;   // 8 x bf16 (4 VGPR)
typedef __attribute__((ext_vector_type(4))) float f32x4;   // MFMA acc

__device__ __forceinline__ u16 f2bf(float f) {
    unsigned u = __float_as_uint(f);
    u += 0x7fffu + ((u >> 16) & 1u);      // round-to-nearest-even
    return (u16)(u >> 16);
}
__device__ __forceinline__ unsigned pkbf2(float a, float b) {
    float2 t; t.x = a; t.y = b;
    __hip_bfloat162 r = __float22bfloat162_rn(t);
    return *(unsigned*)&r;
}
__device__ __forceinline__ float bf2f(short s) {
    return __uint_as_float(((unsigned)(unsigned short)s) << 16);
}
// tanh-form GELU via hw exp2 + rcp (~10 VALU). |err| <= ~3e-3.
__device__ __forceinline__ float gelu_f(float v) {
    float u = v * v;
    float x = v * fmaf(0.0356774081f, u, 0.7978845608f);
    float t = __builtin_amdgcn_exp2f(x * 2.885390082f);    // e^{2x}
    float th = fmaf(-2.0f, __builtin_amdgcn_rcpf(t + 1.0f), 1.0f);
    float hv = 0.5f * v;
    return fmaf(hv, th, hv);
}
// async global->LDS, 16B per lane; lds pointer must be wave-uniform.
__device__ __forceinline__ void glds16(const u16* g, u16* l) {
    __builtin_amdgcn_global_load_lds(
        (const __attribute__((address_space(1))) void*)g,
        (__attribute__((address_space(3))) void*)l, 16, 0, 0);
}
// s_barrier + compiler memory fence: no LDS access may be hoisted above it.
__device__ __forceinline__ void barfence() {
    __builtin_amdgcn_s_barrier();
    asm volatile("" ::: "memory");
}

// --------------------------- weight transpose ------------------------------
__global__ __launch_bounds__(256) void transpose_f32_bf16(
    const float* __restrict__ in, u16* __restrict__ out, int K, int N) {
    __shared__ float t[32][33];
    int n0 = blockIdx.x * 32, k0 = blockIdx.y * 32;
    int c = threadIdx.x, r0 = threadIdx.y;           // block (32,8)
#pragma unroll
    for (int i = 0; i < 4; i++) {
        int r = r0 + i * 8;
        t[r][c] = in[(size_t)(k0 + r) * N + n0 + c];
    }
    __syncthreads();
#pragma unroll
    for (int i = 0; i < 4; i++) {
        int r = r0 + i * 8;
        out[(size_t)(n0 + r) * K + k0 + c] = f2bf(t[c][r]);
    }
}

// ------------------------------ layernorm ----------------------------------
template <bool GELU>
__global__ __launch_bounds__(256) void ln_kernel(
    const float* __restrict__ x, const float* __restrict__ g,
    const float* __restrict__ bt, u16* __restrict__ out) {
    const int D = 1024;
    int row = blockIdx.x;
    float4 v = reinterpret_cast<const float4*>(x + (size_t)row * D)[threadIdx.x];
    float s = v.x + v.y + v.z + v.w;
    float s2 = v.x * v.x + v.y * v.y + v.z * v.z + v.w * v.w;
#pragma unroll
    for (int off = 32; off > 0; off >>= 1) {
        s += __shfl_down(s, off);
        s2 += __shfl_down(s2, off);
    }
    __shared__ float red[8];
    int wid = threadIdx.x >> 6;
    if ((threadIdx.x & 63) == 0) { red[wid] = s; red[wid + 4] = s2; }
    __syncthreads();
    s = red[0] + red[1] + red[2] + red[3];
    s2 = red[4] + red[5] + red[6] + red[7];
    float mu = s * (1.0f / 1024.0f);
    float var = s2 * (1.0f / 1024.0f) - mu * mu;
    float rstd = rsqrtf(var + 1e-5f);
    float4 gg = reinterpret_cast<const float4*>(g)[threadIdx.x];
    float4 bb = reinterpret_cast<const float4*>(bt)[threadIdx.x];
    float o0 = (v.x - mu) * rstd * gg.x + bb.x;
    float o1 = (v.y - mu) * rstd * gg.y + bb.y;
    float o2 = (v.z - mu) * rstd * gg.z + bb.z;
    float o3 = (v.w - mu) * rstd * gg.w + bb.w;
    if (GELU) { o0 = gelu_f(o0); o1 = gelu_f(o1); o2 = gelu_f(o2); o3 = gelu_f(o3); }
    uint2 o;
    o.x = pkbf2(o0, o1); o.y = pkbf2(o2, o3);
    reinterpret_cast<uint2*>(out + (size_t)row * D)[threadIdx.x] = o;
}

// --------------------------- GEMM (256x256) --------------------------------
// R10: one barrier per K-tile. Per tile: issue 24 ds_read_b128 (bfA, af0,
// bfB, af1), issue 8 stage glds16 (tile t+1 -> buf^1), then 64 MFMA in 4
// quadrant clusters, then vmcnt(0)+barrier. Dbuf, 1-ahead.
template <int OUT_BF16, int ACT_GELU, int HAS_RES>
__global__ __launch_bounds__(512, 2) void gemm_kernel(
    const u16* __restrict__ A, const u16* __restrict__ BT,
    const float* __restrict__ bias, const float* __restrict__ res,
    void* __restrict__ outp, int M, int N, int K) {
    __shared__ u16 As[2 * 256 * 64];   // 64 KB
    __shared__ u16 Bs[2 * 256 * 64];   // 64 KB
    const int nwg = gridDim.x * gridDim.y;
    int wg = blockIdx.y * gridDim.x + blockIdx.x;
    wg = (wg & 7) * (nwg >> 3) + (wg >> 3);
    const int m0 = (wg / gridDim.x) * 256, n0 = (wg % gridDim.x) * 256;
    const int tid = threadIdx.x;
    const int w = tid >> 6, lane = tid & 63, l16 = lane & 15, quad = lane >> 4;
    const int wm = w >> 2, wn = w & 3;           // 2 x 4 wave grid

    const int lrow = lane >> 3;                   // 0..7
    const int lcol = ((lane & 7) ^ lrow) * 8;     // swizzled col group
    const u16* Ag = A + (size_t)(m0 + w * 16 + lrow) * K + lcol;
    const u16* Bg = BT + (size_t)(n0 + w * 16 + lrow) * K + lcol;

    const int cx0 = (quad ^ (l16 & 7)) * 8;
    const int cx1 = cx0 ^ 32;

    f32x4 acc[2][2][4][2] = {};                   // [ah][bh][i][j]
    const int nt = K >> 6;

#define STAGE_A(AH, BUF, KK)                                              \
    do {                                                                  \
        const u16* _s = Ag + (size_t)((AH) * 128) * K + (KK);             \
        u16* _d = As + (BUF) * 16384 + ((AH) * 128 + w * 16) * 64;        \
        glds16(_s, _d);                                                   \
        glds16(_s + (size_t)8 * K, _d + 512);                             \
    } while (0)
#define STAGE_B(BH, BUF, KK)                                              \
    do {                                                                  \
        const u16* _s = Bg + (size_t)((BH) * 128) * K + (KK);             \
        u16* _d = Bs + (BUF) * 16384 + ((BH) * 128 + w * 16) * 64;        \
        glds16(_s, _d);                                                   \
        glds16(_s + (size_t)8 * K, _d + 512);                             \
    } while (0)

    STAGE_A(0, 0, 0);
    STAGE_B(0, 0, 0);
    STAGE_B(1, 0, 0);
    STAGE_A(1, 0, 0);
    asm volatile("s_waitcnt vmcnt(0)" ::: "memory");
    barfence();

    s16x8 af0[4][2], af1[4][2], bfA[2][2], bfB[2][2];

    for (int t = 0; t < nt; ++t) {
        const int cur = t & 1, nxt = cur ^ 1;
        const int kk = (t + 1) << 6;
        const bool pre = (t + 1) < nt;
        const u16* Ab = As + cur * 16384;
        const u16* Bb = Bs + cur * 16384;

        // ---- issue all LDS reads for this tile
#pragma unroll
        for (int j = 0; j < 2; ++j) {
            const u16* p = Bb + (wn * 32 + j * 16 + l16) * 64;
            bfA[j][0] = *(const s16x8*)(p + cx0);
            bfA[j][1] = *(const s16x8*)(p + cx1);
        }
#pragma unroll
        for (int i = 0; i < 4; ++i) {
            const u16* p = Ab + (wm * 64 + i * 16 + l16) * 64;
            af0[i][0] = *(const s16x8*)(p + cx0);
            af0[i][1] = *(const s16x8*)(p + cx1);
        }
#pragma unroll
        for (int j = 0; j < 2; ++j) {
            const u16* p = Bb + (128 + wn * 32 + j * 16 + l16) * 64;
            bfB[j][0] = *(const s16x8*)(p + cx0);
            bfB[j][1] = *(const s16x8*)(p + cx1);
        }
#pragma unroll
        for (int i = 0; i < 4; ++i) {
            const u16* p = Ab + (128 + wm * 64 + i * 16 + l16) * 64;
            af1[i][0] = *(const s16x8*)(p + cx0);
            af1[i][1] = *(const s16x8*)(p + cx1);
        }
        // ---- issue next-tile staging (buf^1; no hazard with cur reads)
        if (pre) {
            STAGE_A(0, nxt, kk);
            STAGE_B(0, nxt, kk);
            STAGE_B(1, nxt, kk);
            STAGE_A(1, nxt, kk);
        }
        // ---- 64 MFMA; compiler inserts fine-grained lgkmcnt per dep.
        __builtin_amdgcn_s_setprio(1);
#pragma unroll
        for (int kd = 0; kd < 2; ++kd)
#pragma unroll
            for (int i = 0; i < 4; ++i)
#pragma unroll
                for (int j = 0; j < 2; ++j)
                    acc[0][0][i][j] = __builtin_amdgcn_mfma_f32_16x16x32_bf16(
                        af0[i][kd], bfA[j][kd], acc[0][0][i][j], 0, 0, 0);
#pragma unroll
        for (int kd = 0; kd < 2; ++kd)
#pragma unroll
            for (int i = 0; i < 4; ++i)
#pragma unroll
                for (int j = 0; j < 2; ++j)
                    acc[0][1][i][j] = __builtin_amdgcn_mfma_f32_16x16x32_bf16(
                        af0[i][kd], bfB[j][kd], acc[0][1][i][j], 0, 0, 0);
#pragma unroll
        for (int kd = 0; kd < 2; ++kd)
#pragma unroll
            for (int i = 0; i < 4; ++i)
#pragma unroll
                for (int j = 0; j < 2; ++j)
                    acc[1][1][i][j] = __builtin_amdgcn_mfma_f32_16x16x32_bf16(
                        af1[i][kd], bfB[j][kd], acc[1][1][i][j], 0, 0, 0);
#pragma unroll
        for (int kd = 0; kd < 2; ++kd)
#pragma unroll
            for (int i = 0; i < 4; ++i)
#pragma unroll
                for (int j = 0; j < 2; ++j)
                    acc[1][0][i][j] = __builtin_amdgcn_mfma_f32_16x16x32_bf16(
                        af1[i][kd], bfA[j][kd], acc[1][0][i][j], 0, 0, 0);
        __builtin_amdgcn_s_setprio(0);
        if (pre) {
            asm volatile("s_waitcnt vmcnt(0)" ::: "memory");
            barfence();
        }
    }
#undef STAGE_A
#undef STAGE_B

    float bv[2][2];
#pragma unroll
    for (int bh = 0; bh < 2; ++bh)
#pragma unroll
        for (int j = 0; j < 2; ++j)
            bv[bh][j] = bias[n0 + bh * 128 + wn * 32 + j * 16 + l16];

#pragma unroll
    for (int ah = 0; ah < 2; ++ah)
#pragma unroll
        for (int i = 0; i < 4; ++i) {
            int rowb = m0 + ah * 128 + wm * 64 + i * 16 + quad * 4;
#pragma unroll
            for (int bh = 0; bh < 2; ++bh)
#pragma unroll
                for (int j = 0; j < 2; ++j) {
                    int col = n0 + bh * 128 + wn * 32 + j * 16 + l16;
#pragma unroll
                    for (int r = 0; r < 4; ++r) {
                        float v = acc[ah][bh][i][j][r] + bv[bh][j];
                        if (ACT_GELU) v = gelu_f(v);
                        size_t idx = (size_t)(rowb + r) * N + col;
                        if (HAS_RES) v += res[idx];
                        if (OUT_BF16) ((u16*)outp)[idx] = f2bf(v);
                        else          ((float*)outp)[idx] = v;
                    }
                }
        }
}

// --------------------------- GEMM (256x128) --------------------------------
// R10: one barrier per K-tile. Per tile: issue 16 ds_read_b128 (bfA, af,
// bfB), issue 6 stage glds16 (tile t+2 -> buf b2), 32 MFMA, vmcnt(6)+bar.
// Tri-buffer, 2-ahead. SPLIT_V: V third of qkv written transposed+token-
// permuted to vtg (R9).
template <int OUT_BF16, int HAS_RES, int SPLIT_V>
__global__ __launch_bounds__(512, 2) void gemm_n128(
    const u16* __restrict__ A, const u16* __restrict__ BT,
    const float* __restrict__ bias, const float* __restrict__ res,
    void* __restrict__ outp, u16* __restrict__ vtg, int M, int N, int K) {
    __shared__ u16 As[3 * 256 * 64];   // 96 KB
    __shared__ u16 Bs[3 * 128 * 64];   // 48 KB
    const int nwg = gridDim.x * gridDim.y;
    int wg = blockIdx.y * gridDim.x + blockIdx.x;
    wg = (wg & 7) * (nwg >> 3) + (wg >> 3);
    const int m0 = (wg / gridDim.x) * 256, n0 = (wg % gridDim.x) * 128;
    const int tid = threadIdx.x;
    const int w = tid >> 6, lane = tid & 63, l16 = lane & 15, quad = lane >> 4;
    const int wm = w >> 1, wn = w & 1;           // 4 x 2 wave grid

    const int lrow = lane >> 3;
    const int lcol = ((lane & 7) ^ lrow) * 8;
    const u16* Ag = A + (size_t)(m0 + w * 16 + lrow) * K + lcol;
    const u16* Bg = BT + (size_t)(n0 + w * 16 + lrow) * K + lcol;

    const int cx0 = (quad ^ (l16 & 7)) * 8;
    const int cx1 = cx0 ^ 32;

    f32x4 acc[4][4] = {};                        // [i][j] 64x64
    const int nt = K >> 6;

#define NSTAGE_A(BUF, KK)                                                 \
    do {                                                                  \
        const u16* _s = Ag + (KK);                                        \
        u16* _d = As + (BUF) * 16384 + (w * 16) * 64;                     \
        glds16(_s, _d);                                                   \
        glds16(_s + (size_t)8 * K, _d + 512);                             \
        glds16(_s + (size_t)128 * K, _d + 8192);                          \
        glds16(_s + (size_t)136 * K, _d + 8192 + 512);                    \
    } while (0)
#define NSTAGE_B(BUF, KK)                                                 \
    do {                                                                  \
        const u16* _s = Bg + (KK);                                        \
        u16* _d = Bs + (BUF) * 8192 + (w * 16) * 64;                      \
        glds16(_s, _d);                                                   \
        glds16(_s + (size_t)8 * K, _d + 512);                             \
    } while (0)

    NSTAGE_A(0, 0);
    NSTAGE_B(0, 0);
    NSTAGE_A(1, 64);
    NSTAGE_B(1, 64);
    asm volatile("s_waitcnt vmcnt(6)" ::: "memory");
    barfence();

    s16x8 af[4][2], bfA[2][2], bfB[2][2];
    int cur = 0, b2 = 2;
    for (int t = 0; t < nt; ++t) {
        const bool pre2 = (t + 2) < nt;
        const u16* Ab = As + cur * 16384;
        const u16* Bb = Bs + cur * 8192;
        const int kk2 = (t + 2) << 6;

        // ---- issue all LDS reads for this tile
#pragma unroll
        for (int j = 0; j < 2; ++j) {
            const u16* p = Bb + (wn * 64 + j * 16 + l16) * 64;
            bfA[j][0] = *(const s16x8*)(p + cx0);
            bfA[j][1] = *(const s16x8*)(p + cx1);
        }
#pragma unroll
        for (int i = 0; i < 4; ++i) {
            const u16* p = Ab + (wm * 64 + i * 16 + l16) * 64;
            af[i][0] = *(const s16x8*)(p + cx0);
            af[i][1] = *(const s16x8*)(p + cx1);
        }
#pragma unroll
        for (int j = 0; j < 2; ++j) {
            const u16* p = Bb + (wn * 64 + 32 + j * 16 + l16) * 64;
            bfB[j][0] = *(const s16x8*)(p + cx0);
            bfB[j][1] = *(const s16x8*)(p + cx1);
        }
        // ---- issue tile t+2 staging
        if (pre2) {
            NSTAGE_A(b2, kk2);
            NSTAGE_B(b2, kk2);
        }
        // ---- 32 MFMA
        __builtin_amdgcn_s_setprio(1);
#pragma unroll
        for (int kd = 0; kd < 2; ++kd)
#pragma unroll
            for (int i = 0; i < 4; ++i)
#pragma unroll
                for (int j = 0; j < 2; ++j)
                    acc[i][j] = __builtin_amdgcn_mfma_f32_16x16x32_bf16(
                        af[i][kd], bfA[j][kd], acc[i][j], 0, 0, 0);
#pragma unroll
        for (int kd = 0; kd < 2; ++kd)
#pragma unroll
            for (int i = 0; i < 4; ++i)
#pragma unroll
                for (int j = 0; j < 2; ++j)
                    acc[i][2 + j] = __builtin_amdgcn_mfma_f32_16x16x32_bf16(
                        af[i][kd], bfB[j][kd], acc[i][2 + j], 0, 0, 0);
        __builtin_amdgcn_s_setprio(0);
        if (pre2)               asm volatile("s_waitcnt vmcnt(6)" ::: "memory");
        else if (t + 1 < nt)    asm volatile("s_waitcnt vmcnt(0)" ::: "memory");
        if (t + 1 < nt) barfence();

        cur = (cur == 2) ? 0 : cur + 1;
        b2 = (b2 == 2) ? 0 : b2 + 1;
    }
#undef NSTAGE_A
#undef NSTAGE_B

    float bv[4];
#pragma unroll
    for (int j = 0; j < 4; ++j) bv[j] = bias[n0 + wn * 64 + j * 16 + l16];

    if (SPLIT_V && n0 >= 2048) {
#pragma unroll
        for (int i = 0; i < 4; ++i) {
            int rowb = m0 + wm * 64 + i * 16 + quad * 4;
            int bb = rowb >> 11, tt = rowb & 2047;
            // R9 token permutation within 64-token tile (bijective).
            int tp = (tt & ~63) | (tt & 0x23) | ((tt & 0x0C) << 1) | ((tt & 0x10) >> 2);
#pragma unroll
            for (int j = 0; j < 4; ++j) {
                int vcol = n0 + wn * 64 + j * 16 + l16 - 2048;
                uint2 pk;
                pk.x = pkbf2(acc[i][j][0] + bv[j], acc[i][j][1] + bv[j]);
                pk.y = pkbf2(acc[i][j][2] + bv[j], acc[i][j][3] + bv[j]);
                *(uint2*)&vtg[((size_t)bb * 1024 + vcol) * 2048 + tp] = pk;
            }
        }
    } else {
#pragma unroll
        for (int i = 0; i < 4; ++i) {
            int rowb = m0 + wm * 64 + i * 16 + quad * 4;
#pragma unroll
            for (int j = 0; j < 4; ++j) {
                int col = n0 + wn * 64 + j * 16 + l16;
#pragma unroll
                for (int r = 0; r < 4; ++r) {
                    float v = acc[i][j][r] + bv[j];
                    size_t idx = (size_t)(rowb + r) * N + col;
                    if (HAS_RES) v += res[idx];
                    if (OUT_BF16) ((u16*)outp)[idx] = f2bf(v);
                    else          ((float*)outp)[idx] = v;
                }
            }
        }
    }
}

// ------------------------------ K norms ------------------------------------
__global__ __launch_bounds__(256) void knorm_kernel(
    const u16* __restrict__ qkv, float* __restrict__ maxkn) {
    const int T = 2048, D3 = 3072;
    int bh = blockIdx.x, b = bh >> 4, h = bh & 15;
    const u16* kg = qkv + (size_t)b * T * D3 + 1024 + h * 64;
    float mx = 0.f;
#pragma unroll
    for (int i = 0; i < 8; i++) {
        const u16* kp = kg + (size_t)(threadIdx.x + i * 256) * D3;
        float ss = 0.f;
#pragma unroll
        for (int c = 0; c < 8; c++) {
            s16x8 v = *(const s16x8*)(kp + c * 8);
#pragma unroll
            for (int j = 0; j < 8; j++) { float f = bf2f(v[j]); ss = fmaf(f, f, ss); }
        }
        mx = fmaxf(mx, ss);
    }
#pragma unroll
    for (int off = 32; off > 0; off >>= 1) mx = fmaxf(mx, __shfl_down(mx, off));
    __shared__ float red[4];
    if ((threadIdx.x & 63) == 0) red[threadIdx.x >> 6] = mx;
    __syncthreads();
    if (threadIdx.x == 0)
        maxkn[bh] = sqrtf(fmaxf(fmaxf(red[0], red[1]), fmaxf(red[2], red[3])));
}

// ----------------------------- flash attention -----------------------------
// R9: glds16 dbuf K/V staging + XOR LDS (zero-conflict reads), P fully in
// registers via producer-side vtg token permutation. Unchanged in R10.
__global__ __launch_bounds__(256, 4) void attn_kernel(
    const u16* __restrict__ qkv, const u16* __restrict__ vtg,
    const float* __restrict__ maxkn, u16* __restrict__ o) {
    const int T = 2048, D3 = 3072, Dm = 1024;
    const int bh = blockIdx.x, qb = blockIdx.y;
    const int b = bh >> 4, h = bh & 15;
    const int tid = threadIdx.x;
    const int w = tid >> 6, lane = tid & 63, l16 = lane & 15, quad = lane >> 4;
    const size_t tokbase = (size_t)b * T;
    const float s2 = 0.125f * 1.44269504088896f;   // scale * log2(e)

    __shared__ u16 Ks[2][64 * 64];     // K tile [key][dim], XOR layout
    __shared__ u16 Vts[2][64 * 64];    // V^T tile [dim][perm-key], XOR layout

    s16x8 bq[2][2];
    float m2[2];
    const float kn = maxkn[bh];
#pragma unroll
    for (int qs = 0; qs < 2; qs++) {
        int qrow = qb * 128 + w * 32 + qs * 16 + l16;
        const u16* qp = qkv + (tokbase + qrow) * D3 + h * 64 + quad * 8;
        bq[qs][0] = *(const s16x8*)qp;
        bq[qs][1] = *(const s16x8*)(qp + 32);
        float ss = 0.f;
#pragma unroll
        for (int kd = 0; kd < 2; kd++)
#pragma unroll
            for (int j = 0; j < 8; j++) {
                float v = bf2f(bq[qs][kd][j]); ss = fmaf(v, v, ss);
            }
        ss += __shfl_xor(ss, 16);
        ss += __shfl_xor(ss, 32);
        m2[qs] = sqrtf(ss) * kn * s2;
    }

    f32x4 acc_ot[2][4] = {};
    float lp[2] = {0.f, 0.f};

    const int lr = lane >> 3;
    const int lcs = ((lane & 7) ^ lr) * 8;
    const u16* kgl = qkv + tokbase * D3 + 1024 + h * 64 + (size_t)(w * 16 + lr) * D3 + lcs;
    const u16* vgl = vtg + ((size_t)b * 1024 + h * 64 + w * 16 + lr) * T + lcs;

    const int cq0 = (quad ^ (l16 & 7)) * 8;
    const int cq1 = cq0 ^ 32;

#define ASTAGE(BUF, KT)                                                   \
    do {                                                                  \
        const u16* _k = kgl + (size_t)(KT) * 64 * D3;                     \
        glds16(_k, &Ks[BUF][(w * 16) * 64]);                              \
        glds16(_k + (size_t)8 * D3, &Ks[BUF][(w * 16 + 8) * 64]);         \
        const u16* _v = vgl + (KT) * 64;                                  \
        glds16(_v, &Vts[BUF][(w * 16) * 64]);                             \
        glds16(_v + (size_t)8 * T, &Vts[BUF][(w * 16 + 8) * 64]);         \
    } while (0)

    ASTAGE(0, 0);
    asm volatile("s_waitcnt vmcnt(0)" ::: "memory");
    barfence();

    for (int kt = 0; kt < 32; kt++) {
        const int cur = kt & 1;
        if (kt + 1 < 32) ASTAGE(cur ^ 1, kt + 1);   // async prefetch

        // S^T = K Q^T
        f32x4 st[2][4] = {};
        __builtin_amdgcn_s_setprio(1);
#pragma unroll
        for (int kd = 0; kd < 2; kd++)
#pragma unroll
            for (int kb = 0; kb < 4; kb++) {
                s16x8 ak = *(const s16x8*)&Ks[cur][(kb * 16 + l16) * 64 + (kd ? cq1 : cq0)];
#pragma unroll
                for (int qs = 0; qs < 2; qs++)
                    st[qs][kb] = __builtin_amdgcn_mfma_f32_16x16x32_bf16(
                        ak, bq[qs][kd], st[qs][kb], 0, 0, 0);
            }
        __builtin_amdgcn_s_setprio(0);

        // p = exp2(s*s2 - m2); deferred l; P stays in registers.
        unsigned px[2][4], py[2][4];
#pragma unroll
        for (int qs = 0; qs < 2; qs++) {
            float acc_l = 0.f;
#pragma unroll
            for (int kb = 0; kb < 4; kb++) {
#pragma unroll
                for (int r = 0; r < 4; r++) {
                    float pv = __builtin_amdgcn_exp2f(fmaf(st[qs][kb][r], s2, -m2[qs]));
                    st[qs][kb][r] = pv;
                    acc_l += pv;
                }
                px[qs][kb] = pkbf2(st[qs][kb][0], st[qs][kb][1]);
                py[qs][kb] = pkbf2(st[qs][kb][2], st[qs][kb][3]);
            }
            lp[qs] += acc_l;
        }

        // O^T += V^T P^T : B-operand lane-local under the vtg permutation.
#pragma unroll
        for (int kk = 0; kk < 2; kk++) {
            s16x8 bp[2];
#pragma unroll
            for (int qs = 0; qs < 2; qs++) {
                union { s16x8 v; unsigned u[4]; } bb;
                bb.u[0] = px[qs][2 * kk];
                bb.u[1] = py[qs][2 * kk];
                bb.u[2] = px[qs][2 * kk + 1];
                bb.u[3] = py[qs][2 * kk + 1];
                bp[qs] = bb.v;
            }
            __builtin_amdgcn_s_setprio(1);
#pragma unroll
            for (int dt = 0; dt < 4; dt++) {
                s16x8 av = *(const s16x8*)&Vts[cur][(dt * 16 + l16) * 64 + (kk ? cq1 : cq0)];
#pragma unroll
                for (int qs = 0; qs < 2; qs++)
                    acc_ot[qs][dt] = __builtin_amdgcn_mfma_f32_16x16x32_bf16(
                        av, bp[qs], acc_ot[qs][dt], 0, 0, 0);
            }
            __builtin_amdgcn_s_setprio(0);
        }

        if (kt + 1 < 32) asm volatile("s_waitcnt vmcnt(0)" ::: "memory");
        barfence();
    }
#undef ASTAGE

#pragma unroll
    for (int qs = 0; qs < 2; qs++) {
        float l = lp[qs];
        l += __shfl_xor(l, 16);
        l += __shfl_xor(l, 32);
        float inv = 1.0f / l;
        int token = qb * 128 + w * 32 + qs * 16 + l16;
#pragma unroll
        for (int dt = 0; dt < 4; dt++) {
            uint2 pk;
            pk.x = pkbf2(acc_ot[qs][dt][0] * inv, acc_ot[qs][dt][1] * inv);
            pk.y = pkbf2(acc_ot[qs][dt][2] * inv, acc_ot[qs][dt][3] * inv);
            *(uint2*)&o[(tokbase + token) * Dm + h * 64 + dt * 16 + quad * 4] = pk;
        }
    }
}

// ------------------------------- launcher ----------------------------------
extern "C" void kernel_launch(void* const* d_in, const int* in_sizes, int n_in,
                              void* d_out, int out_size, void* d_ws, size_t ws_size,
                              hipStream_t stream) {
    const int M = 8192;   // B*T
    const int D = 1024, D3 = 3072, FF = 4096;

    const float* x      = (const float*)d_in[0];
    const float* ln1_g  = (const float*)d_in[1];
    const float* ln1_b  = (const float*)d_in[2];
    const float* W_ap   = (const float*)d_in[3];
    const float* b_ap   = (const float*)d_in[4];
    const float* W_qkv  = (const float*)d_in[5];
    const float* b_qkv  = (const float*)d_in[6];
    const float* W_proj = (const float*)d_in[7];
    const float* b_proj = (const float*)d_in[8];
    const float* ln2_g  = (const float*)d_in[9];
    const float* ln2_b  = (const float*)d_in[10];
    const float* W1     = (const float*)d_in[11];
    const float* b1     = (const float*)d_in[12];
    const float* W2     = (const float*)d_in[13];
    const float* b2     = (const float*)d_in[14];

    char* p = (char*)d_ws;
    auto carve = [&](size_t bytes) { char* r = p; p += (bytes + 255) & ~(size_t)255; return r; };
    u16*   WapT   = (u16*)carve((size_t)D * D * 2);
    u16*   WqkvT  = (u16*)carve((size_t)D * D3 * 2);
    u16*   WprojT = (u16*)carve((size_t)D * D * 2);
    u16*   W1T    = (u16*)carve((size_t)D * FF * 2);
    u16*   W2T    = (u16*)carve((size_t)FF * D * 2);
    u16*   aln    = (u16*)carve((size_t)M * D * 2);    // reused as gbuf
    u16*   a1     = (u16*)carve((size_t)M * D * 2);    // reused as obuf
    u16*   qkvb   = (u16*)carve((size_t)M * D3 * 2);
    float* hbuf   = (float*)carve((size_t)M * D * 4);
    u16*   f1     = (u16*)carve((size_t)M * FF * 2);
    float* maxkn  = (float*)carve(64 * 4);
    u16* gbuf = aln;
    u16* obuf = a1;
    u16* vtg  = f1;   // V^T [b,h,dim,2048] (16MB) overlaps f1: dead before W1 GEMM

    dim3 tb(32, 8);
    transpose_f32_bf16<<<dim3(D / 32, D / 32), tb, 0, stream>>>(W_ap, WapT, D, D);
    transpose_f32_bf16<<<dim3(D3 / 32, D / 32), tb, 0, stream>>>(W_qkv, WqkvT, D, D3);
    transpose_f32_bf16<<<dim3(D / 32, D / 32), tb, 0, stream>>>(W_proj, WprojT, D, D);
    transpose_f32_bf16<<<dim3(FF / 32, D / 32), tb, 0, stream>>>(W1, W1T, D, FF);
    transpose_f32_bf16<<<dim3(D / 32, FF / 32), tb, 0, stream>>>(W2, W2T, FF, D);

    // a = LN1(x)
    ln_kernel<false><<<M, 256, 0, stream>>>(x, ln1_g, ln1_b, aln);
    // a1 = a @ W_ap + b_ap   (N=1024 -> full-chip n128 variant)
    gemm_n128<1, 0, 0><<<dim3(D / 128, M / 256), 512, 0, stream>>>(
        aln, WapT, b_ap, nullptr, a1, nullptr, M, D, D);
    // qkv = a1 @ W_qkv + b_qkv  (n128: 768 blocks; V -> vtg, permuted)
    gemm_n128<1, 0, 1><<<dim3(D3 / 128, M / 256), 512, 0, stream>>>(
        a1, WqkvT, b_qkv, nullptr, qkvb, vtg, M, D3, D);
    // per-(b,h) max K-norm for the softmax bound
    knorm_kernel<<<64, 256, 0, stream>>>(qkvb, maxkn);
    // o = attention(qkv, vtg)
    attn_kernel<<<dim3(64, 16), 256, 0, stream>>>(qkvb, vtg, maxkn, obuf);
    // h = x + o @ W_proj + b_proj   (fp32, n128)
    gemm_n128<0, 1, 0><<<dim3(D / 128, M / 256), 512, 0, stream>>>(
        obuf, WprojT, b_proj, x, hbuf, nullptr, M, D, D);
    // g = gelu(LN2(h))
    ln_kernel<true><<<M, 256, 0, stream>>>(hbuf, ln2_g, ln2_b, gbuf);
    // f1 = gelu(g @ W1 + b1)   (256x256 kernel, 512 blocks = 2 full rounds)
    gemm_kernel<1, 1, 0><<<dim3(FF / 256, M / 256), 512, 0, stream>>>(
        gbuf, W1T, b1, nullptr, f1, M, FF, D);
    // out = h + f1 @ W2 + b2   (fp32, n128)
    gemm_n128<0, 1, 0><<<dim3(D / 128, M / 256), 512, 0, stream>>>(
        f1, W2T, b2, hbuf, (float*)d_out, nullptr, M, D, FF);
}

// Round 8
// 518.237 us; speedup vs baseline: 1.0304x; 1.0304x over previous
//
#include <hip/hip_runtime.h>
#include <hip/hip_bf16.h>
#include <math.h>

// ---------------------------------------------------------------------------
// Transformer block fwd: B=4,T=2048,D=1024,H=16,HS=64,FF=4096, fp32 in/out,
// bf16 MFMA internally. Residual path (x, h, out) kept fp32.
// R7: gemm_n128 (full-chip) for N=1024 GEMMs, tri-buffer 2-ahead vmcnt(6).
// R8: attn glds16 dbuf staging + XOR LDS.  R9: P lane-local via vtg token
//     permutation (attn bank conflicts = 0 measured).
// R11: deep-pipeline gemm256 for qkv/W1 (see ledger in gemm256 comment).
// R12: resubmit after infra failure; full hazard/vmcnt/barrier audit passed
//     (ledger closed at steady state and endgame nt=16; every overwrite
//     separated from its last reader by a barrier; uniform barrier counts).
// ---------------------------------------------------------------------------

typedef unsigned short u16;
typedef __attribute__((ext_vector_type(8))) short s16x8;   // 8 x bf16 (4 VGPR)
typedef __attribute__((ext_vector_type(4))) float f32x4;   // MFMA acc

__device__ __forceinline__ u16 f2bf(float f) {
    unsigned u = __float_as_uint(f);
    u += 0x7fffu + ((u >> 16) & 1u);      // round-to-nearest-even
    return (u16)(u >> 16);
}
__device__ __forceinline__ unsigned pkbf2(float a, float b) {
    float2 t; t.x = a; t.y = b;
    __hip_bfloat162 r = __float22bfloat162_rn(t);
    return *(unsigned*)&r;
}
__device__ __forceinline__ float bf2f(short s) {
    return __uint_as_float(((unsigned)(unsigned short)s) << 16);
}
// tanh-form GELU via hw exp2 + rcp (~10 VALU). |err| <= ~3e-3.
__device__ __forceinline__ float gelu_f(float v) {
    float u = v * v;
    float x = v * fmaf(0.0356774081f, u, 0.7978845608f);
    float t = __builtin_amdgcn_exp2f(x * 2.885390082f);    // e^{2x}
    float th = fmaf(-2.0f, __builtin_amdgcn_rcpf(t + 1.0f), 1.0f);
    float hv = 0.5f * v;
    return fmaf(hv, th, hv);
}
// async global->LDS, 16B per lane; lds pointer must be wave-uniform.
__device__ __forceinline__ void glds16(const u16* g, u16* l) {
    __builtin_amdgcn_global_load_lds(
        (const __attribute__((address_space(1))) void*)g,
        (__attribute__((address_space(3))) void*)l, 16, 0, 0);
}
// s_barrier + compiler memory fence: no LDS access may be hoisted above it.
__device__ __forceinline__ void barfence() {
    __builtin_amdgcn_s_barrier();
    asm volatile("" ::: "memory");
}

// --------------------------- weight transpose ------------------------------
__global__ __launch_bounds__(256) void transpose_f32_bf16(
    const float* __restrict__ in, u16* __restrict__ out, int K, int N) {
    __shared__ float t[32][33];
    int n0 = blockIdx.x * 32, k0 = blockIdx.y * 32;
    int c = threadIdx.x, r0 = threadIdx.y;           // block (32,8)
#pragma unroll
    for (int i = 0; i < 4; i++) {
        int r = r0 + i * 8;
        t[r][c] = in[(size_t)(k0 + r) * N + n0 + c];
    }
    __syncthreads();
#pragma unroll
    for (int i = 0; i < 4; i++) {
        int r = r0 + i * 8;
        out[(size_t)(n0 + r) * K + k0 + c] = f2bf(t[c][r]);
    }
}

// ------------------------------ layernorm ----------------------------------
template <bool GELU>
__global__ __launch_bounds__(256) void ln_kernel(
    const float* __restrict__ x, const float* __restrict__ g,
    const float* __restrict__ bt, u16* __restrict__ out) {
    const int D = 1024;
    int row = blockIdx.x;
    float4 v = reinterpret_cast<const float4*>(x + (size_t)row * D)[threadIdx.x];
    float s = v.x + v.y + v.z + v.w;
    float s2 = v.x * v.x + v.y * v.y + v.z * v.z + v.w * v.w;
#pragma unroll
    for (int off = 32; off > 0; off >>= 1) {
        s += __shfl_down(s, off);
        s2 += __shfl_down(s2, off);
    }
    __shared__ float red[8];
    int wid = threadIdx.x >> 6;
    if ((threadIdx.x & 63) == 0) { red[wid] = s; red[wid + 4] = s2; }
    __syncthreads();
    s = red[0] + red[1] + red[2] + red[3];
    s2 = red[4] + red[5] + red[6] + red[7];
    float mu = s * (1.0f / 1024.0f);
    float var = s2 * (1.0f / 1024.0f) - mu * mu;
    float rstd = rsqrtf(var + 1e-5f);
    float4 gg = reinterpret_cast<const float4*>(g)[threadIdx.x];
    float4 bb = reinterpret_cast<const float4*>(bt)[threadIdx.x];
    float o0 = (v.x - mu) * rstd * gg.x + bb.x;
    float o1 = (v.y - mu) * rstd * gg.y + bb.y;
    float o2 = (v.z - mu) * rstd * gg.z + bb.z;
    float o3 = (v.w - mu) * rstd * gg.w + bb.w;
    if (GELU) { o0 = gelu_f(o0); o1 = gelu_f(o1); o2 = gelu_f(o2); o3 = gelu_f(o3); }
    uint2 o;
    o.x = pkbf2(o0, o1); o.y = pkbf2(o2, o3);
    reinterpret_cast<uint2*>(out + (size_t)row * D)[threadIdx.x] = o;
}

// ----------------------- GEMM 256x256 deep pipeline ------------------------
// 8 waves 2Mx4N; per-wave quadrants (ah,bh) of 64x32; snake order
// (0,0),(0,1),(1,1),(1,0): af reused (A0 live P0-P1, A1 live P2-P3),
// bfA live P0..P3, bfB live P1-P2.
// Ledger (2 loads/half/lane): stage@t.P0->A1(t+1)@nxt; P1->A0(t+2)@cur;
// P2->B0(t+2)@cur; P3->B1(t+2)@cur (mid-tile slot reuse; slots released by
// the P0/P1/P3 barriers). Tile T's halves staged at (T-2).P1,P2,P3,(T-1).P0
// -> issue-to-wait 6-7 phases (> HBM latency). Waits (each immediately
// before a barrier; vmcnt is per-wave, cross-wave visibility via barrier):
// end-P0 vmcnt(10) -> T's B1 done; end-P1 vmcnt(10) -> T's A1 done;
// end-P3 vmcnt(10) -> (T+1)'s A0,B0 done. Endgame nt=16 verified:
// t=14: 10/8/4; t=15: 2/0/-. 3 barriers/K-tile.
// SPLIT_V: blocks with n0>=2048 (V third of qkv) write transposed+token-
// permuted to vtg (R9) instead of outp.
template <int OUT_BF16, int ACT_GELU, int SPLIT_V>
__global__ __launch_bounds__(512, 2) void gemm256(
    const u16* __restrict__ A, const u16* __restrict__ BT,
    const float* __restrict__ bias, void* __restrict__ outp,
    u16* __restrict__ vtg, int M, int N, int K) {
    __shared__ u16 As[2 * 256 * 64];   // 64 KB
    __shared__ u16 Bs[2 * 256 * 64];   // 64 KB
    const int nwg = gridDim.x * gridDim.y;
    int wg = blockIdx.y * gridDim.x + blockIdx.x;
    wg = (wg & 7) * (nwg >> 3) + (wg >> 3);
    const int m0 = (wg / gridDim.x) * 256, n0 = (wg % gridDim.x) * 256;
    const int tid = threadIdx.x;
    const int w = tid >> 6, lane = tid & 63, l16 = lane & 15, quad = lane >> 4;
    const int wm = w >> 2, wn = w & 3;           // 2 x 4 wave grid

    const int lrow = lane >> 3;                   // 0..7
    const int lcol = ((lane & 7) ^ lrow) * 8;     // swizzled col group
    const u16* Ag = A + (size_t)(m0 + w * 16 + lrow) * K + lcol;
    const u16* Bg = BT + (size_t)(n0 + w * 16 + lrow) * K + lcol;

    const int cx0 = (quad ^ (l16 & 7)) * 8;
    const int cx1 = cx0 ^ 32;

    f32x4 acc[2][2][4][2] = {};                   // [ah][bh][i][j]
    const int nt = K >> 6;

// stage half H (0/1) of A/B into buffer C with data k-offset KK (2 glds16)
#define SA(C, H, KK)                                                      \
    do {                                                                  \
        const u16* _s = Ag + (size_t)((H) * 128) * K + (KK);              \
        u16* _d = As + (C) * 16384 + ((H) * 128 + w * 16) * 64;           \
        glds16(_s, _d);                                                   \
        glds16(_s + (size_t)8 * K, _d + 512);                             \
    } while (0)
#define SB(C, H, KK)                                                      \
    do {                                                                  \
        const u16* _s = Bg + (size_t)((H) * 128) * K + (KK);              \
        u16* _d = Bs + (C) * 16384 + ((H) * 128 + w * 16) * 64;           \
        glds16(_s, _d);                                                   \
        glds16(_s + (size_t)8 * K, _d + 512);                             \
    } while (0)

    // prologue: tile0 full (A0,B0,B1,A1 = consumption order) + tile1 partial
    // (A0,B0,B1; A1(1) staged at t0.P0). vmcnt(6) keeps tile1's 6 in flight.
    SA(0, 0, 0); SB(0, 0, 0); SB(0, 1, 0); SA(0, 1, 0);
    SA(1, 0, 64); SB(1, 0, 64); SB(1, 1, 64);
    asm volatile("s_waitcnt vmcnt(6)" ::: "memory");
    barfence();

    s16x8 af[4][2], bfA[2][2], bfB[2][2];

    for (int t = 0; t < nt; ++t) {
        const int cur = t & 1, nxt = cur ^ 1;
        const u16* Ab = As + cur * 16384;
        const u16* Bb = Bs + cur * 16384;
        const int kk1 = (t + 1) << 6, kk2 = (t + 2) << 6;
        const bool s1 = (t + 1) < nt, s2 = (t + 2) < nt;

        // ---- P0: (0,0). reads A0-frags + B0-frags; stage A1(t+1)@nxt.
#pragma unroll
        for (int i = 0; i < 4; ++i) {
            const u16* p = Ab + (wm * 64 + i * 16 + l16) * 64;
            af[i][0] = *(const s16x8*)(p + cx0);
            af[i][1] = *(const s16x8*)(p + cx1);
        }
#pragma unroll
        for (int j = 0; j < 2; ++j) {
            const u16* p = Bb + (wn * 32 + j * 16 + l16) * 64;
            bfA[j][0] = *(const s16x8*)(p + cx0);
            bfA[j][1] = *(const s16x8*)(p + cx1);
        }
        if (s1) SA(nxt, 1, kk1);
        asm volatile("s_waitcnt lgkmcnt(0)" ::: "memory");
        __builtin_amdgcn_sched_barrier(0);
        __builtin_amdgcn_s_setprio(1);
#pragma unroll
        for (int kd = 0; kd < 2; ++kd)
#pragma unroll
            for (int i = 0; i < 4; ++i)
#pragma unroll
                for (int j = 0; j < 2; ++j)
                    acc[0][0][i][j] = __builtin_amdgcn_mfma_f32_16x16x32_bf16(
                        af[i][kd], bfA[j][kd], acc[0][0][i][j], 0, 0, 0);
        __builtin_amdgcn_s_setprio(0);
        if (t < nt - 1) asm volatile("s_waitcnt vmcnt(10)" ::: "memory");
        else            asm volatile("s_waitcnt vmcnt(2)" ::: "memory");
        barfence();   // releases A0,B0 slots; guards P1's B1 read

        // ---- P1: (0,1). reads B1-frags; stage A0(t+2)@cur (slot released).
#pragma unroll
        for (int j = 0; j < 2; ++j) {
            const u16* p = Bb + (128 + wn * 32 + j * 16 + l16) * 64;
            bfB[j][0] = *(const s16x8*)(p + cx0);
            bfB[j][1] = *(const s16x8*)(p + cx1);
        }
        if (s2) SA(cur, 0, kk2);
        asm volatile("s_waitcnt lgkmcnt(0)" ::: "memory");
        __builtin_amdgcn_sched_barrier(0);
        __builtin_amdgcn_s_setprio(1);
#pragma unroll
        for (int kd = 0; kd < 2; ++kd)
#pragma unroll
            for (int i = 0; i < 4; ++i)
#pragma unroll
                for (int j = 0; j < 2; ++j)
                    acc[0][1][i][j] = __builtin_amdgcn_mfma_f32_16x16x32_bf16(
                        af[i][kd], bfB[j][kd], acc[0][1][i][j], 0, 0, 0);
        __builtin_amdgcn_s_setprio(0);
        if (s2)      asm volatile("s_waitcnt vmcnt(10)" ::: "memory");
        else if (s1) asm volatile("s_waitcnt vmcnt(8)" ::: "memory");
        else         asm volatile("s_waitcnt vmcnt(0)" ::: "memory");
        barfence();   // releases B1 slot; guards P2's A1 read

        // ---- P2: (1,1). reads A1-frags (af reused); stage B0(t+2)@cur.
        // No barrier: af1 reads complete (lgkm0) before any wave passes
        // P3's barrier, which precedes the (t+1).P0 stage overwriting A1.
#pragma unroll
        for (int i = 0; i < 4; ++i) {
            const u16* p = Ab + (128 + wm * 64 + i * 16 + l16) * 64;
            af[i][0] = *(const s16x8*)(p + cx0);
            af[i][1] = *(const s16x8*)(p + cx1);
        }
        if (s2) SB(cur, 0, kk2);
        asm volatile("s_waitcnt lgkmcnt(0)" ::: "memory");
        __builtin_amdgcn_sched_barrier(0);
        __builtin_amdgcn_s_setprio(1);
#pragma unroll
        for (int kd = 0; kd < 2; ++kd)
#pragma unroll
            for (int i = 0; i < 4; ++i)
#pragma unroll
                for (int j = 0; j < 2; ++j)
                    acc[1][1][i][j] = __builtin_amdgcn_mfma_f32_16x16x32_bf16(
                        af[i][kd], bfB[j][kd], acc[1][1][i][j], 0, 0, 0);
        __builtin_amdgcn_s_setprio(0);

        // ---- P3: (1,0). no reads (af1,bfA in regs); stage B1(t+2)@cur.
        if (s2) SB(cur, 1, kk2);
        __builtin_amdgcn_s_setprio(1);
#pragma unroll
        for (int kd = 0; kd < 2; ++kd)
#pragma unroll
            for (int i = 0; i < 4; ++i)
#pragma unroll
                for (int j = 0; j < 2; ++j)
                    acc[1][0][i][j] = __builtin_amdgcn_mfma_f32_16x16x32_bf16(
                        af[i][kd], bfA[j][kd], acc[1][0][i][j], 0, 0, 0);
        __builtin_amdgcn_s_setprio(0);
        if (s2) {
            asm volatile("s_waitcnt vmcnt(10)" ::: "memory");
            barfence();
        } else if (s1) {
            asm volatile("s_waitcnt vmcnt(4)" ::: "memory");
            barfence();
        }
        // t == nt-1: fall through to epilogue
    }
#undef SA
#undef SB

    float bv[2][2];
#pragma unroll
    for (int bh = 0; bh < 2; ++bh)
#pragma unroll
        for (int j = 0; j < 2; ++j)
            bv[bh][j] = bias[n0 + bh * 128 + wn * 32 + j * 16 + l16];

    if (SPLIT_V && n0 >= 2048) {
#pragma unroll
        for (int ah = 0; ah < 2; ++ah)
#pragma unroll
            for (int i = 0; i < 4; ++i) {
                int rowb = m0 + ah * 128 + wm * 64 + i * 16 + quad * 4;
                int bb = rowb >> 11, tt = rowb & 2047;
                // R9 token permutation within 64-token tile (bijective).
                int tp = (tt & ~63) | (tt & 0x23) | ((tt & 0x0C) << 1) | ((tt & 0x10) >> 2);
#pragma unroll
                for (int bh = 0; bh < 2; ++bh)
#pragma unroll
                    for (int j = 0; j < 2; ++j) {
                        int vcol = n0 + bh * 128 + wn * 32 + j * 16 + l16 - 2048;
                        uint2 pk;
                        pk.x = pkbf2(acc[ah][bh][i][j][0] + bv[bh][j],
                                     acc[ah][bh][i][j][1] + bv[bh][j]);
                        pk.y = pkbf2(acc[ah][bh][i][j][2] + bv[bh][j],
                                     acc[ah][bh][i][j][3] + bv[bh][j]);
                        *(uint2*)&vtg[((size_t)bb * 1024 + vcol) * 2048 + tp] = pk;
                    }
            }
    } else {
#pragma unroll
        for (int ah = 0; ah < 2; ++ah)
#pragma unroll
            for (int i = 0; i < 4; ++i) {
                int rowb = m0 + ah * 128 + wm * 64 + i * 16 + quad * 4;
#pragma unroll
                for (int bh = 0; bh < 2; ++bh)
#pragma unroll
                    for (int j = 0; j < 2; ++j) {
                        int col = n0 + bh * 128 + wn * 32 + j * 16 + l16;
#pragma unroll
                        for (int r = 0; r < 4; ++r) {
                            float v = acc[ah][bh][i][j][r] + bv[bh][j];
                            if (ACT_GELU) v = gelu_f(v);
                            size_t idx = (size_t)(rowb + r) * N + col;
                            if (OUT_BF16) ((u16*)outp)[idx] = f2bf(v);
                            else          ((float*)outp)[idx] = v;
                        }
                    }
            }
    }
}

// --------------------------- GEMM (256x128) --------------------------------
// Full-chip variant for N=1024 outputs (R6/R10 form, unchanged as control).
template <int OUT_BF16, int HAS_RES, int SPLIT_V>
__global__ __launch_bounds__(512, 2) void gemm_n128(
    const u16* __restrict__ A, const u16* __restrict__ BT,
    const float* __restrict__ bias, const float* __restrict__ res,
    void* __restrict__ outp, u16* __restrict__ vtg, int M, int N, int K) {
    __shared__ u16 As[3 * 256 * 64];   // 96 KB
    __shared__ u16 Bs[3 * 128 * 64];   // 48 KB
    const int nwg = gridDim.x * gridDim.y;
    int wg = blockIdx.y * gridDim.x + blockIdx.x;
    wg = (wg & 7) * (nwg >> 3) + (wg >> 3);
    const int m0 = (wg / gridDim.x) * 256, n0 = (wg % gridDim.x) * 128;
    const int tid = threadIdx.x;
    const int w = tid >> 6, lane = tid & 63, l16 = lane & 15, quad = lane >> 4;
    const int wm = w >> 1, wn = w & 1;           // 4 x 2 wave grid

    const int lrow = lane >> 3;
    const int lcol = ((lane & 7) ^ lrow) * 8;
    const u16* Ag = A + (size_t)(m0 + w * 16 + lrow) * K + lcol;
    const u16* Bg = BT + (size_t)(n0 + w * 16 + lrow) * K + lcol;

    const int cx0 = (quad ^ (l16 & 7)) * 8;
    const int cx1 = cx0 ^ 32;

    f32x4 acc[4][4] = {};                        // [i][j] 64x64
    const int nt = K >> 6;

#define NSTAGE_A(BUF, KK)                                                 \
    do {                                                                  \
        const u16* _s = Ag + (KK);                                        \
        u16* _d = As + (BUF) * 16384 + (w * 16) * 64;                     \
        glds16(_s, _d);                                                   \
        glds16(_s + (size_t)8 * K, _d + 512);                             \
        glds16(_s + (size_t)128 * K, _d + 8192);                          \
        glds16(_s + (size_t)136 * K, _d + 8192 + 512);                    \
    } while (0)
#define NSTAGE_B(BUF, KK)                                                 \
    do {                                                                  \
        const u16* _s = Bg + (KK);                                        \
        u16* _d = Bs + (BUF) * 8192 + (w * 16) * 64;                      \
        glds16(_s, _d);                                                   \
        glds16(_s + (size_t)8 * K, _d + 512);                             \
    } while (0)

    NSTAGE_A(0, 0);
    NSTAGE_B(0, 0);
    NSTAGE_A(1, 64);
    NSTAGE_B(1, 64);
    asm volatile("s_waitcnt vmcnt(6)" ::: "memory");
    barfence();

    s16x8 af[4][2], bfA[2][2], bfB[2][2];
    int cur = 0, b2 = 2;
    for (int t = 0; t < nt; ++t) {
        const bool pre2 = (t + 2) < nt;
        const u16* Ab = As + cur * 16384;
        const u16* Bb = Bs + cur * 8192;
        const int kk2 = (t + 2) << 6;

#pragma unroll
        for (int j = 0; j < 2; ++j) {
            const u16* p = Bb + (wn * 64 + j * 16 + l16) * 64;
            bfA[j][0] = *(const s16x8*)(p + cx0);
            bfA[j][1] = *(const s16x8*)(p + cx1);
        }
#pragma unroll
        for (int i = 0; i < 4; ++i) {
            const u16* p = Ab + (wm * 64 + i * 16 + l16) * 64;
            af[i][0] = *(const s16x8*)(p + cx0);
            af[i][1] = *(const s16x8*)(p + cx1);
        }
#pragma unroll
        for (int j = 0; j < 2; ++j) {
            const u16* p = Bb + (wn * 64 + 32 + j * 16 + l16) * 64;
            bfB[j][0] = *(const s16x8*)(p + cx0);
            bfB[j][1] = *(const s16x8*)(p + cx1);
        }
        if (pre2) {
            NSTAGE_A(b2, kk2);
            NSTAGE_B(b2, kk2);
        }
        __builtin_amdgcn_s_setprio(1);
#pragma unroll
        for (int kd = 0; kd < 2; ++kd)
#pragma unroll
            for (int i = 0; i < 4; ++i)
#pragma unroll
                for (int j = 0; j < 2; ++j)
                    acc[i][j] = __builtin_amdgcn_mfma_f32_16x16x32_bf16(
                        af[i][kd], bfA[j][kd], acc[i][j], 0, 0, 0);
#pragma unroll
        for (int kd = 0; kd < 2; ++kd)
#pragma unroll
            for (int i = 0; i < 4; ++i)
#pragma unroll
                for (int j = 0; j < 2; ++j)
                    acc[i][2 + j] = __builtin_amdgcn_mfma_f32_16x16x32_bf16(
                        af[i][kd], bfB[j][kd], acc[i][2 + j], 0, 0, 0);
        __builtin_amdgcn_s_setprio(0);
        if (pre2)               asm volatile("s_waitcnt vmcnt(6)" ::: "memory");
        else if (t + 1 < nt)    asm volatile("s_waitcnt vmcnt(0)" ::: "memory");
        if (t + 1 < nt) barfence();

        cur = (cur == 2) ? 0 : cur + 1;
        b2 = (b2 == 2) ? 0 : b2 + 1;
    }
#undef NSTAGE_A
#undef NSTAGE_B

    float bv[4];
#pragma unroll
    for (int j = 0; j < 4; ++j) bv[j] = bias[n0 + wn * 64 + j * 16 + l16];

    if (SPLIT_V && n0 >= 2048) {
#pragma unroll
        for (int i = 0; i < 4; ++i) {
            int rowb = m0 + wm * 64 + i * 16 + quad * 4;
            int bb = rowb >> 11, tt = rowb & 2047;
            int tp = (tt & ~63) | (tt & 0x23) | ((tt & 0x0C) << 1) | ((tt & 0x10) >> 2);
#pragma unroll
            for (int j = 0; j < 4; ++j) {
                int vcol = n0 + wn * 64 + j * 16 + l16 - 2048;
                uint2 pk;
                pk.x = pkbf2(acc[i][j][0] + bv[j], acc[i][j][1] + bv[j]);
                pk.y = pkbf2(acc[i][j][2] + bv[j], acc[i][j][3] + bv[j]);
                *(uint2*)&vtg[((size_t)bb * 1024 + vcol) * 2048 + tp] = pk;
            }
        }
    } else {
#pragma unroll
        for (int i = 0; i < 4; ++i) {
            int rowb = m0 + wm * 64 + i * 16 + quad * 4;
#pragma unroll
            for (int j = 0; j < 4; ++j) {
                int col = n0 + wn * 64 + j * 16 + l16;
#pragma unroll
                for (int r = 0; r < 4; ++r) {
                    float v = acc[i][j][r] + bv[j];
                    size_t idx = (size_t)(rowb + r) * N + col;
                    if (HAS_RES) v += res[idx];
                    if (OUT_BF16) ((u16*)outp)[idx] = f2bf(v);
                    else          ((float*)outp)[idx] = v;
                }
            }
        }
    }
}

// ------------------------------ K norms ------------------------------------
__global__ __launch_bounds__(256) void knorm_kernel(
    const u16* __restrict__ qkv, float* __restrict__ maxkn) {
    const int T = 2048, D3 = 3072;
    int bh = blockIdx.x, b = bh >> 4, h = bh & 15;
    const u16* kg = qkv + (size_t)b * T * D3 + 1024 + h * 64;
    float mx = 0.f;
#pragma unroll
    for (int i = 0; i < 8; i++) {
        const u16* kp = kg + (size_t)(threadIdx.x + i * 256) * D3;
        float ss = 0.f;
#pragma unroll
        for (int c = 0; c < 8; c++) {
            s16x8 v = *(const s16x8*)(kp + c * 8);
#pragma unroll
            for (int j = 0; j < 8; j++) { float f = bf2f(v[j]); ss = fmaf(f, f, ss); }
        }
        mx = fmaxf(mx, ss);
    }
#pragma unroll
    for (int off = 32; off > 0; off >>= 1) mx = fmaxf(mx, __shfl_down(mx, off));
    __shared__ float red[4];
    if ((threadIdx.x & 63) == 0) red[threadIdx.x >> 6] = mx;
    __syncthreads();
    if (threadIdx.x == 0)
        maxkn[bh] = sqrtf(fmaxf(fmaxf(red[0], red[1]), fmaxf(red[2], red[3])));
}

// ----------------------------- flash attention -----------------------------
// R9 form, unchanged: glds16 dbuf K/V staging + XOR LDS (zero-conflict),
// P fully in registers via producer-side vtg token permutation.
__global__ __launch_bounds__(256, 4) void attn_kernel(
    const u16* __restrict__ qkv, const u16* __restrict__ vtg,
    const float* __restrict__ maxkn, u16* __restrict__ o) {
    const int T = 2048, D3 = 3072, Dm = 1024;
    const int bh = blockIdx.x, qb = blockIdx.y;
    const int b = bh >> 4, h = bh & 15;
    const int tid = threadIdx.x;
    const int w = tid >> 6, lane = tid & 63, l16 = lane & 15, quad = lane >> 4;
    const size_t tokbase = (size_t)b * T;
    const float s2 = 0.125f * 1.44269504088896f;   // scale * log2(e)

    __shared__ u16 Ks[2][64 * 64];     // K tile [key][dim], XOR layout
    __shared__ u16 Vts[2][64 * 64];    // V^T tile [dim][perm-key], XOR layout

    s16x8 bq[2][2];
    float m2[2];
    const float kn = maxkn[bh];
#pragma unroll
    for (int qs = 0; qs < 2; qs++) {
        int qrow = qb * 128 + w * 32 + qs * 16 + l16;
        const u16* qp = qkv + (tokbase + qrow) * D3 + h * 64 + quad * 8;
        bq[qs][0] = *(const s16x8*)qp;
        bq[qs][1] = *(const s16x8*)(qp + 32);
        float ss = 0.f;
#pragma unroll
        for (int kd = 0; kd < 2; kd++)
#pragma unroll
            for (int j = 0; j < 8; j++) {
                float v = bf2f(bq[qs][kd][j]); ss = fmaf(v, v, ss);
            }
        ss += __shfl_xor(ss, 16);
        ss += __shfl_xor(ss, 32);
        m2[qs] = sqrtf(ss) * kn * s2;
    }

    f32x4 acc_ot[2][4] = {};
    float lp[2] = {0.f, 0.f};

    const int lr = lane >> 3;
    const int lcs = ((lane & 7) ^ lr) * 8;
    const u16* kgl = qkv + tokbase * D3 + 1024 + h * 64 + (size_t)(w * 16 + lr) * D3 + lcs;
    const u16* vgl = vtg + ((size_t)b * 1024 + h * 64 + w * 16 + lr) * T + lcs;

    const int cq0 = (quad ^ (l16 & 7)) * 8;
    const int cq1 = cq0 ^ 32;

#define ASTAGE(BUF, KT)                                                   \
    do {                                                                  \
        const u16* _k = kgl + (size_t)(KT) * 64 * D3;                     \
        glds16(_k, &Ks[BUF][(w * 16) * 64]);                              \
        glds16(_k + (size_t)8 * D3, &Ks[BUF][(w * 16 + 8) * 64]);         \
        const u16* _v = vgl + (KT) * 64;                                  \
        glds16(_v, &Vts[BUF][(w * 16) * 64]);                             \
        glds16(_v + (size_t)8 * T, &Vts[BUF][(w * 16 + 8) * 64]);         \
    } while (0)

    ASTAGE(0, 0);
    asm volatile("s_waitcnt vmcnt(0)" ::: "memory");
    barfence();

    for (int kt = 0; kt < 32; kt++) {
        const int cur = kt & 1;
        if (kt + 1 < 32) ASTAGE(cur ^ 1, kt + 1);   // async prefetch

        f32x4 st[2][4] = {};
        __builtin_amdgcn_s_setprio(1);
#pragma unroll
        for (int kd = 0; kd < 2; kd++)
#pragma unroll
            for (int kb = 0; kb < 4; kb++) {
                s16x8 ak = *(const s16x8*)&Ks[cur][(kb * 16 + l16) * 64 + (kd ? cq1 : cq0)];
#pragma unroll
                for (int qs = 0; qs < 2; qs++)
                    st[qs][kb] = __builtin_amdgcn_mfma_f32_16x16x32_bf16(
                        ak, bq[qs][kd], st[qs][kb], 0, 0, 0);
            }
        __builtin_amdgcn_s_setprio(0);

        unsigned px[2][4], py[2][4];
#pragma unroll
        for (int qs = 0; qs < 2; qs++) {
            float acc_l = 0.f;
#pragma unroll
            for (int kb = 0; kb < 4; kb++) {
#pragma unroll
                for (int r = 0; r < 4; r++) {
                    float pv = __builtin_amdgcn_exp2f(fmaf(st[qs][kb][r], s2, -m2[qs]));
                    st[qs][kb][r] = pv;
                    acc_l += pv;
                }
                px[qs][kb] = pkbf2(st[qs][kb][0], st[qs][kb][1]);
                py[qs][kb] = pkbf2(st[qs][kb][2], st[qs][kb][3]);
            }
            lp[qs] += acc_l;
        }

#pragma unroll
        for (int kk = 0; kk < 2; kk++) {
            s16x8 bp[2];
#pragma unroll
            for (int qs = 0; qs < 2; qs++) {
                union { s16x8 v; unsigned u[4]; } bb;
                bb.u[0] = px[qs][2 * kk];
                bb.u[1] = py[qs][2 * kk];
                bb.u[2] = px[qs][2 * kk + 1];
                bb.u[3] = py[qs][2 * kk + 1];
                bp[qs] = bb.v;
            }
            __builtin_amdgcn_s_setprio(1);
#pragma unroll
            for (int dt = 0; dt < 4; dt++) {
                s16x8 av = *(const s16x8*)&Vts[cur][(dt * 16 + l16) * 64 + (kk ? cq1 : cq0)];
#pragma unroll
                for (int qs = 0; qs < 2; qs++)
                    acc_ot[qs][dt] = __builtin_amdgcn_mfma_f32_16x16x32_bf16(
                        av, bp[qs], acc_ot[qs][dt], 0, 0, 0);
            }
            __builtin_amdgcn_s_setprio(0);
        }

        if (kt + 1 < 32) asm volatile("s_waitcnt vmcnt(0)" ::: "memory");
        barfence();
    }
#undef ASTAGE

#pragma unroll
    for (int qs = 0; qs < 2; qs++) {
        float l = lp[qs];
        l += __shfl_xor(l, 16);
        l += __shfl_xor(l, 32);
        float inv = 1.0f / l;
        int token = qb * 128 + w * 32 + qs * 16 + l16;
#pragma unroll
        for (int dt = 0; dt < 4; dt++) {
            uint2 pk;
            pk.x = pkbf2(acc_ot[qs][dt][0] * inv, acc_ot[qs][dt][1] * inv);
            pk.y = pkbf2(acc_ot[qs][dt][2] * inv, acc_ot[qs][dt][3] * inv);
            *(uint2*)&o[(tokbase + token) * Dm + h * 64 + dt * 16 + quad * 4] = pk;
        }
    }
}

// ------------------------------- launcher ----------------------------------
extern "C" void kernel_launch(void* const* d_in, const int* in_sizes, int n_in,
                              void* d_out, int out_size, void* d_ws, size_t ws_size,
                              hipStream_t stream) {
    const int M = 8192;   // B*T
    const int D = 1024, D3 = 3072, FF = 4096;

    const float* x      = (const float*)d_in[0];
    const float* ln1_g  = (const float*)d_in[1];
    const float* ln1_b  = (const float*)d_in[2];
    const float* W_ap   = (const float*)d_in[3];
    const float* b_ap   = (const float*)d_in[4];
    const float* W_qkv  = (const float*)d_in[5];
    const float* b_qkv  = (const float*)d_in[6];
    const float* W_proj = (const float*)d_in[7];
    const float* b_proj = (const float*)d_in[8];
    const float* ln2_g  = (const float*)d_in[9];
    const float* ln2_b  = (const float*)d_in[10];
    const float* W1     = (const float*)d_in[11];
    const float* b1     = (const float*)d_in[12];
    const float* W2     = (const float*)d_in[13];
    const float* b2     = (const float*)d_in[14];

    char* p = (char*)d_ws;
    auto carve = [&](size_t bytes) { char* r = p; p += (bytes + 255) & ~(size_t)255; return r; };
    u16*   WapT   = (u16*)carve((size_t)D * D * 2);
    u16*   WqkvT  = (u16*)carve((size_t)D * D3 * 2);
    u16*   WprojT = (u16*)carve((size_t)D * D * 2);
    u16*   W1T    = (u16*)carve((size_t)D * FF * 2);
    u16*   W2T    = (u16*)carve((size_t)FF * D * 2);
    u16*   aln    = (u16*)carve((size_t)M * D * 2);    // reused as gbuf
    u16*   a1     = (u16*)carve((size_t)M * D * 2);    // reused as obuf
    u16*   qkvb   = (u16*)carve((size_t)M * D3 * 2);
    float* hbuf   = (float*)carve((size_t)M * D * 4);
    u16*   f1     = (u16*)carve((size_t)M * FF * 2);
    float* maxkn  = (float*)carve(64 * 4);
    u16* gbuf = aln;
    u16* obuf = a1;
    u16* vtg  = f1;   // V^T [b,h,dim,2048] (16MB) overlaps f1: dead before W1 GEMM

    dim3 tb(32, 8);
    transpose_f32_bf16<<<dim3(D / 32, D / 32), tb, 0, stream>>>(W_ap, WapT, D, D);
    transpose_f32_bf16<<<dim3(D3 / 32, D / 32), tb, 0, stream>>>(W_qkv, WqkvT, D, D3);
    transpose_f32_bf16<<<dim3(D / 32, D / 32), tb, 0, stream>>>(W_proj, WprojT, D, D);
    transpose_f32_bf16<<<dim3(FF / 32, D / 32), tb, 0, stream>>>(W1, W1T, D, FF);
    transpose_f32_bf16<<<dim3(D / 32, FF / 32), tb, 0, stream>>>(W2, W2T, FF, D);

    // a = LN1(x)
    ln_kernel<false><<<M, 256, 0, stream>>>(x, ln1_g, ln1_b, aln);
    // a1 = a @ W_ap + b_ap   (n128, unchanged control)
    gemm_n128<1, 0, 0><<<dim3(D / 128, M / 256), 512, 0, stream>>>(
        aln, WapT, b_ap, nullptr, a1, nullptr, M, D, D);
    // qkv = a1 @ W_qkv + b_qkv  (deep gemm256; V -> vtg, permuted)
    gemm256<1, 0, 1><<<dim3(D3 / 256, M / 256), 512, 0, stream>>>(
        a1, WqkvT, b_qkv, qkvb, vtg, M, D3, D);
    // per-(b,h) max K-norm for the softmax bound
    knorm_kernel<<<64, 256, 0, stream>>>(qkvb, maxkn);
    // o = attention(qkv, vtg)
    attn_kernel<<<dim3(64, 16), 256, 0, stream>>>(qkvb, vtg, maxkn, obuf);
    // h = x + o @ W_proj + b_proj   (fp32, n128, control)
    gemm_n128<0, 1, 0><<<dim3(D / 128, M / 256), 512, 0, stream>>>(
        obuf, WprojT, b_proj, x, hbuf, nullptr, M, D, D);
    // g = gelu(LN2(h))
    ln_kernel<true><<<M, 256, 0, stream>>>(hbuf, ln2_g, ln2_b, gbuf);
    // f1 = gelu(g @ W1 + b1)   (deep gemm256, 512 blocks = 2 full rounds)
    gemm256<1, 1, 0><<<dim3(FF / 256, M / 256), 512, 0, stream>>>(
        gbuf, W1T, b1, f1, nullptr, M, FF, D);
    // out = h + f1 @ W2 + b2   (fp32, n128, control)
    gemm_n128<0, 1, 0><<<dim3(D / 128, M / 256), 512, 0, stream>>>(
        f1, W2T, b2, hbuf, (float*)d_out, nullptr, M, D, FF);
}